// Round 7
// baseline (265.525 us; speedup 1.0000x reference)
//
#include <hip/hip_runtime.h>
#include <hip/hip_bf16.h>

#define NN    100000
#define KD    500
#define KP    512    // K padded (W zero-filled)
#define HID   64
#define LWS   264    // LDS row stride (bf16 elems) for a 256-wide K chunk
#define GSP   16     // g1/g2 row stride (floats) = 64 B -> one cache line per row
#define DB    128    // dst rows per bucket
#define NB    782    // ceil(NN/DB)
#define CHUNK 4096   // edges per block in histogram/fill

typedef short frag8 __attribute__((ext_vector_type(8)));
typedef float f32x4 __attribute__((ext_vector_type(4)));

static __device__ __forceinline__ unsigned short f2b(float f) {
    return __builtin_bit_cast(unsigned short, __float2bfloat16(f));
}

// ---------------- Kernel 0: W1 fp32 -> bf16, zero-padded to K=512 ----------------
__global__ __launch_bounds__(256) void k0_w1bf(const float* __restrict__ W1,
                                               unsigned short* __restrict__ W1bf)
{
    const int i = blockIdx.x * 256 + threadIdx.x;   // 0..32767
    const int c = i >> 9;        // col 0..63
    const int k = i & 511;
    const float v = (k < KD) ? W1[c * KD + k] : 0.f;
    W1bf[i] = f2b(v);
}

// ---------------- Kernel 1: h = relu(x @ W1^T), bf16 MFMA ----------------
__global__ __launch_bounds__(256, 4) void k1_mfma(const float* __restrict__ x,
                                                  const unsigned short* __restrict__ W1bf,
                                                  float* __restrict__ h, int n)
{
    __shared__ unsigned short lw[64 * LWS];
    const int tid   = threadIdx.x;
    const int lane  = tid & 63;
    const int wid   = tid >> 6;
    const int l15   = lane & 15;
    const int l4    = lane >> 4;     // 0..3
    const int koffl = 8 * l4;        // lane's k sub-offset within a 32-k step

    const long rowBlk = (long)blockIdx.x * 64;
    long ra = rowBlk + wid * 16 + l15;
    if (ra >= n) ra = n - 1;                 // clamp; stores are guarded
    const float* xp = x + ra * KD + koffl;

    f32x4 acc[4] = {};
    const float4 z = make_float4(0.f, 0.f, 0.f, 0.f);

    for (int c = 0; c < 2; ++c) {
        if (c) __syncthreads();
        #pragma unroll
        for (int it = 0; it < 8; ++it) {
            const int idx = tid + it * 256;      // 0..2047
            const int r   = idx >> 5;            // 0..63
            const int q   = idx & 31;            // ushort8 index
            *(uint4*)&lw[r * LWS + q * 8] =
                *(const uint4*)&W1bf[r * KP + c * 256 + q * 8];
        }
        __syncthreads();

        int k0 = c * 256;
        float4 lo = (k0 + koffl     < KD) ? *(const float4*)(xp + k0)     : z;
        float4 hi = (k0 + koffl + 4 < KD) ? *(const float4*)(xp + k0 + 4) : z;

        #pragma unroll
        for (int ks = 0; ks < 8; ++ks) {
            float4 nlo = z, nhi = z;
            if (ks < 7) {
                const int kn = c * 256 + (ks + 1) * 32;
                nlo = (kn + koffl     < KD) ? *(const float4*)(xp + kn)     : z;
                nhi = (kn + koffl + 4 < KD) ? *(const float4*)(xp + kn + 4) : z;
            }
            frag8 a;
            a[0]=f2b(lo.x); a[1]=f2b(lo.y); a[2]=f2b(lo.z); a[3]=f2b(lo.w);
            a[4]=f2b(hi.x); a[5]=f2b(hi.y); a[6]=f2b(hi.z); a[7]=f2b(hi.w);
            const int koffw = ks * 32 + koffl;
            #pragma unroll
            for (int g = 0; g < 4; ++g) {
                const frag8 b = *(const frag8*)&lw[(g * 16 + l15) * LWS + koffw];
                acc[g] = __builtin_amdgcn_mfma_f32_16x16x32_bf16(a, b, acc[g], 0, 0, 0);
            }
            lo = nlo; hi = nhi;
        }
    }

    #pragma unroll
    for (int r = 0; r < 4; ++r) {
        const long row = rowBlk + wid * 16 + l4 * 4 + r;
        if (row < n) {
            #pragma unroll
            for (int g = 0; g < 4; ++g)
                h[row * HID + g * 16 + l15] = fmaxf(acc[g][r], 0.f);
        }
    }
}

// ---------------- Kernel 2: projections ----------------
// out = h @ WfA^T ; g1[:,0:10) = h @ WfB^T ; g2[:,0:10) = h @ WfC^T
__global__ __launch_bounds__(256) void k2_proj(const float* __restrict__ h,
                                               const float* __restrict__ Wf,
                                               float* __restrict__ out,
                                               float* __restrict__ g1,
                                               float* __restrict__ g2, int n)
{
    __shared__ float lwf[10 * 196];
    const int tid = threadIdx.x;
    for (int idx = tid; idx < 480; idx += 256) {
        const int j = idx / 48;
        const int q = idx - j * 48;
        const float4 v = *(const float4*)&Wf[j * 192 + 4 * q];
        *(float4*)&lwf[j * 196 + 4 * q] = v;
    }
    __syncthreads();

    const long row = (long)blockIdx.x * 8 + (tid >> 5);
    const int  j   = tid & 31;
    if (row < n && j < 30) {
        const int wrow = (j < 10) ? j : ((j < 20) ? j - 10 : j - 20);
        const int coff = (j < 10) ? 0 : ((j < 20) ? 64 : 128);
        const float* wp = &lwf[wrow * 196 + coff];
        const float* hp = &h[row * HID];
        float s = 0.f;
        #pragma unroll
        for (int q = 0; q < 16; ++q) {
            const float4 hv = *(const float4*)&hp[4 * q];
            const float4 wv = *(const float4*)&wp[4 * q];
            s += hv.x * wv.x + hv.y * wv.y + hv.z * wv.z + hv.w * wv.w;
        }
        if (j < 10)      out[row * 10 + j] = s;
        else if (j < 20) g1[row * GSP + (j - 10)] = s;
        else             g2[row * GSP + (j - 20)] = s;
    }
}

// ---------------- Kernel A: per-(bucket,block) edge histogram ----------------
__global__ __launch_bounds__(256) void kA_hist(const int* __restrict__ dst1, int nnz1,
                                               const int* __restrict__ dst2, int ntE,
                                               int nblk, int* __restrict__ Cmat)
{
    __shared__ int cnt[NB];
    const int tid = threadIdx.x, blk = blockIdx.x;
    for (int i = tid; i < NB; i += 256) cnt[i] = 0;
    __syncthreads();
    const int base = blk * CHUNK;
    #pragma unroll
    for (int it = 0; it < CHUNK / 256; ++it) {
        const int id = base + it * 256 + tid;
        if (id < ntE) {
            const int d = (id < nnz1) ? dst1[id] : dst2[id - nnz1];
            atomicAdd(&cnt[d / DB], 1);
        }
    }
    __syncthreads();
    for (int b = tid; b < NB; b += 256) Cmat[b * nblk + blk] = cnt[b];
}

// ---------------- Kernel S1: exclusive scan of each bucket row ----------------
__global__ __launch_bounds__(256) void kS1_rowscan(const int* __restrict__ Cmat, int nblk,
                                                   int* __restrict__ OFFmat,
                                                   int* __restrict__ rowSum)
{
    __shared__ int ls[256];
    const int b = blockIdx.x, tid = threadIdx.x;
    const int i0 = 2 * tid, i1 = 2 * tid + 1;
    const int e0 = (i0 < nblk) ? Cmat[b * nblk + i0] : 0;
    const int e1 = (i1 < nblk) ? Cmat[b * nblk + i1] : 0;
    const int ps = e0 + e1;
    ls[tid] = ps;
    __syncthreads();
    for (int off = 1; off < 256; off <<= 1) {
        const int v = (tid >= off) ? ls[tid - off] : 0;
        __syncthreads();
        ls[tid] += v;
        __syncthreads();
    }
    const int excl = ls[tid] - ps;
    if (i0 < nblk) OFFmat[b * nblk + i0] = excl;
    if (i1 < nblk) OFFmat[b * nblk + i1] = excl + e0;
    if (tid == 255) rowSum[b] = ls[255];
}

// ---------------- Kernel S2: exclusive scan of bucket totals ----------------
__global__ __launch_bounds__(256) void kS2_basescan(const int* __restrict__ rowSum,
                                                    int* __restrict__ rowBase)
{
    __shared__ int ls[256];
    const int tid = threadIdx.x;
    int e[4]; int s = 0;
    #pragma unroll
    for (int u = 0; u < 4; ++u) {
        const int i = 4 * tid + u;
        e[u] = (i < NB) ? rowSum[i] : 0;
        s += e[u];
    }
    ls[tid] = s;
    __syncthreads();
    for (int off = 1; off < 256; off <<= 1) {
        const int v = (tid >= off) ? ls[tid - off] : 0;
        __syncthreads();
        ls[tid] += v;
        __syncthreads();
    }
    int run = ls[tid] - s;
    #pragma unroll
    for (int u = 0; u < 4; ++u) {
        const int i = 4 * tid + u;
        if (i < NB) rowBase[i] = run;
        run += e[u];
    }
}

// ---------------- Kernel C: fill buckets with packed edge records ----------------
// rec.x = src | hop<<17 | dstLocal<<18 ; rec.y = bitcast(val)
__global__ __launch_bounds__(256) void kC_fill(const int* __restrict__ src1,
                                               const int* __restrict__ dst1,
                                               const float* __restrict__ val1, int nnz1,
                                               const int* __restrict__ src2,
                                               const int* __restrict__ dst2,
                                               const float* __restrict__ val2, int ntE,
                                               int nblk,
                                               const int* __restrict__ OFFmat,
                                               const int* __restrict__ rowBase,
                                               uint2* __restrict__ bins)
{
    __shared__ int cur[NB];
    const int tid = threadIdx.x, blk = blockIdx.x;
    for (int b = tid; b < NB; b += 256)
        cur[b] = rowBase[b] + OFFmat[b * nblk + blk];
    __syncthreads();
    const int base = blk * CHUNK;
    #pragma unroll
    for (int it = 0; it < CHUNK / 256; ++it) {
        const int id = base + it * 256 + tid;
        if (id < ntE) {
            const bool h1 = id < nnz1;
            const int  ii = h1 ? id : id - nnz1;
            const int   s = h1 ? src1[ii] : src2[ii];
            const int   d = h1 ? dst1[ii] : dst2[ii];
            const float v = h1 ? val1[ii] : val2[ii];
            const int   b = d / DB;
            const int slot = atomicAdd(&cur[b], 1);
            uint2 r;
            r.x = (unsigned)s | ((unsigned)(!h1) << 17) | ((unsigned)(d - b * DB) << 18);
            r.y = __builtin_bit_cast(unsigned, v);
            bins[slot] = r;
        }
    }
}

// ---------------- Kernel D: per-bucket LDS accumulate + coalesced out update ----
__global__ __launch_bounds__(256) void kD_acc(const uint2* __restrict__ bins,
                                              const int* __restrict__ rowBase,
                                              const int* __restrict__ rowSum,
                                              const float* __restrict__ g1,
                                              const float* __restrict__ g2,
                                              float* __restrict__ out)
{
    __shared__ float lacc[DB * 10];
    const int tid = threadIdx.x, b = blockIdx.x;
    for (int i = tid; i < DB * 10; i += 256) lacc[i] = 0.f;
    __syncthreads();
    const int start = rowBase[b];
    const int cnt   = rowSum[b];
    const int nt    = cnt * 10;
    for (int i = tid; i < nt; i += 256) {
        const int e = (int)((unsigned)i / 10u);
        const int j = i - 10 * e;
        const uint2 r = bins[start + e];
        const int   src = r.x & 0x1FFFF;
        const int   hop = (r.x >> 17) & 1;
        const int   dl  = (int)(r.x >> 18);
        const float v   = __builtin_bit_cast(float, r.y);
        const float* gp = hop ? g2 : g1;
        atomicAdd(&lacc[dl * 10 + j], v * gp[(size_t)src * GSP + j]);
    }
    __syncthreads();
    const int rows = min(DB, NN - b * DB);
    float* op = out + (size_t)b * DB * 10;
    for (int i = tid; i < rows * 10; i += 256)
        op[i] += lacc[i];
}

// ---------------- Fallback: direct scatter (agent-scope atomics) ----------------
__global__ __launch_bounds__(256) void k_scatter_dir(const int* __restrict__ src1,
                                                     const int* __restrict__ dst1,
                                                     const float* __restrict__ val1, int n1,
                                                     const int* __restrict__ src2,
                                                     const int* __restrict__ dst2,
                                                     const float* __restrict__ val2, int nt,
                                                     const float* __restrict__ g1,
                                                     const float* __restrict__ g2,
                                                     float* __restrict__ out)
{
    const int t = blockIdx.x * 256 + threadIdx.x;
    if (t >= nt) return;
    const bool h1 = t < n1;
    const int  tt = h1 ? t : t - n1;
    const int  e  = (int)((unsigned)tt / 10u);
    const int  j  = tt - 10 * e;
    const int* sp = h1 ? src1 : src2;
    const int* dp = h1 ? dst1 : dst2;
    const float* vp = h1 ? val1 : val2;
    const float* gp = h1 ? g1 : g2;
    unsafeAtomicAdd(&out[(size_t)dp[e] * 10 + j],
                    vp[e] * gp[(size_t)sp[e] * GSP + j]);
}

extern "C" void kernel_launch(void* const* d_in, const int* in_sizes, int n_in,
                              void* d_out, int out_size, void* d_ws, size_t ws_size,
                              hipStream_t stream)
{
    const float* x    = (const float*)d_in[0];
    const float* W1   = (const float*)d_in[1];
    const float* Wf   = (const float*)d_in[2];
    const int*   src1 = (const int*)d_in[3];
    const int*   dst1 = (const int*)d_in[4];
    const float* val1 = (const float*)d_in[5];
    const int*   src2 = (const int*)d_in[6];
    const int*   dst2 = (const int*)d_in[7];
    const float* val2 = (const float*)d_in[8];
    const int nnz1 = in_sizes[3];
    const int nnz2 = in_sizes[6];
    const int ntE  = nnz1 + nnz2;
    const int n = NN;
    const int nblk = (ntE + CHUNK - 1) / CHUNK;

    char* p = (char*)d_ws;
    unsigned short* W1bf = (unsigned short*)p;       p += (size_t)64 * KP * 2;   // 64 KB
    float* h    = (float*)p;                         p += (size_t)NN * HID * 4;  // 25.6 MB
    float* g1   = (float*)p;                         p += (size_t)NN * GSP * 4;  //  6.4 MB
    float* g2   = (float*)p;                         p += (size_t)NN * GSP * 4;  //  6.4 MB
    uint2* bins = (uint2*)p;                         p += (size_t)ntE * 8;       // 14.4 MB
    int* Cmat   = (int*)p;                           p += (size_t)NB * nblk * 4; //  1.4 MB
    int* OFFmat = (int*)p;                           p += (size_t)NB * nblk * 4; //  1.4 MB
    int* rowSum = (int*)p;                           p += (size_t)NB * 4;
    int* rowBase= (int*)p;                           p += (size_t)NB * 4;
    float* out  = (float*)d_out;                     // [NN][10]
    const size_t ws_need = (size_t)(p - (char*)d_ws);

    k0_w1bf<<<128, 256, 0, stream>>>(W1, W1bf);
    k1_mfma<<<(n + 63) / 64, 256, 0, stream>>>(x, W1bf, h, n);
    k2_proj<<<(n + 7) / 8, 256, 0, stream>>>(h, Wf, out, g1, g2, n);

    if (ws_size >= ws_need) {
        kA_hist<<<nblk, 256, 0, stream>>>(dst1, nnz1, dst2, ntE, nblk, Cmat);
        kS1_rowscan<<<NB, 256, 0, stream>>>(Cmat, nblk, OFFmat, rowSum);
        kS2_basescan<<<1, 256, 0, stream>>>(rowSum, rowBase);
        kC_fill<<<nblk, 256, 0, stream>>>(src1, dst1, val1, nnz1,
                                          src2, dst2, val2, ntE,
                                          nblk, OFFmat, rowBase, bins);
        kD_acc<<<NB, 256, 0, stream>>>(bins, rowBase, rowSum, g1, g2, out);
    } else {
        const int n1 = 10 * nnz1;
        const int nt = n1 + 10 * nnz2;
        k_scatter_dir<<<(nt + 255) / 256, 256, 0, stream>>>(src1, dst1, val1, n1,
                                                            src2, dst2, val2, nt,
                                                            g1, g2, out);
    }
}